// Round 4
// baseline (2107.339 us; speedup 1.0000x reference)
//
#include <hip/hip_runtime.h>

typedef float v2f __attribute__((ext_vector_type(2)));

#define VOCABN 5000
#define EMBD   16
#define HIDN   32
#define GATES  128   // 4*HID
#define BATCH  512
#define SEQT   2048

__device__ __forceinline__ float sigm(float x) {
    return __builtin_amdgcn_rcpf(1.0f + __expf(-x));
}
__device__ __forceinline__ float tanh_fast(float x) {
    float s = __builtin_amdgcn_rcpf(1.0f + __expf(-2.0f * x));
    return __builtin_fmaf(2.0f, s, -1.0f);
}

// proj[v*64 + l] = { emb[v]·W[:,l] + bias[l],  emb[v]·W[:,l+64] + bias[l+64] }
__global__ __launch_bounds__(64) void build_proj_kernel(
    const float* __restrict__ emb, const float* __restrict__ W,
    const float* __restrict__ bias, v2f* __restrict__ proj)
{
    const int v = blockIdx.x;
    const int l = threadIdx.x;
    float e[EMBD];
#pragma unroll
    for (int k = 0; k < EMBD; ++k) e[k] = emb[v * EMBD + k];
    float a = bias[l];
    float b = bias[l + 64];
#pragma unroll
    for (int k = 0; k < EMBD; ++k) {
        a = __builtin_fmaf(e[k], W[k * GATES + l], a);
        b = __builtin_fmaf(e[k], W[k * GATES + l + 64], b);
    }
    proj[v * 64 + l] = (v2f){a, b};
}

// One 64-lane wave per batch row. Lane l owns gates l and l+64.
// h[j] is duplicated in lanes j and j+32; broadcast of h[k] to all lanes is a
// single ds_swizzle (BitMode or_mask=k) within each 32-lane half — no LDS
// buffer, no barriers, compiler-tracked lgkmcnt.
__global__ __launch_bounds__(64) void lstm_scan_kernel(
    const int* __restrict__ tokens, const float* __restrict__ rec,
    const v2f* __restrict__ proj, float* __restrict__ out)
{
    const int b = blockIdx.x;
    const int l = threadIdx.x;

    // rec_kernel columns l and l+64, packed for v_pk_fma_f32 (64 VGPRs)
    v2f rab[HIDN];
#pragma unroll
    for (int k = 0; k < HIDN; ++k) {
        rab[k] = (v2f){ rec[k * GATES + l], rec[k * GATES + l + 64] };
    }

    const int* __restrict__ trow = tokens + (size_t)b * SEQT;
    const bool lo = (l < HIDN);

    float c = 0.0f, hval = 0.0f;

    // depth-2 prefetch for the proj gather (covers ~2 steps of L2 latency),
    // tokens fetched 3 ahead (uniform -> scalar loads)
    int tok0 = trow[0];
    int tok1 = trow[1];
    int tok2 = trow[2];
    v2f xz0 = proj[(size_t)tok0 * 64 + l];
    v2f xz1 = proj[(size_t)tok1 * 64 + l];

    for (int t = 0; t < SEQT; ++t) {
        v2f xz2 = proj[(size_t)tok2 * 64 + l];
        const int t3 = t + 3;
        const int tok3 = trow[t3 < SEQT ? t3 : SEQT - 1];

        // z = xz + h @ rec (columns l, l+64); 4 split accumulators for latency
        v2f a0 = xz0;
        v2f a1 = (v2f){0.f, 0.f};
        v2f a2 = (v2f){0.f, 0.f};
        v2f a3 = (v2f){0.f, 0.f};

#define STEP_K(kk, acc) {                                                        \
        float hk = __int_as_float(                                               \
            __builtin_amdgcn_ds_swizzle(__float_as_int(hval), (kk) << 5));       \
        v2f hh = (v2f){ hk, hk };                                                \
        acc = __builtin_elementwise_fma(hh, rab[kk], acc); }
#define K4(base) STEP_K(base + 0, a0) STEP_K(base + 1, a1) \
                 STEP_K(base + 2, a2) STEP_K(base + 3, a3)
        K4(0) K4(4) K4(8) K4(12) K4(16) K4(20) K4(24) K4(28)
#undef K4
#undef STEP_K

        const v2f zz = (a0 + a1) + (a2 + a3);
        const float zA = zz.x;
        const float zB = zz.y;

        // exchange halves: lane j<32 holds (i,g), lane j+32 holds (f,o)
        const float sA = __shfl_xor(zA, 32, 64);
        const float sB = __shfl_xor(zB, 32, 64);
        const float zi = lo ? zA : sA;
        const float zf = lo ? sA : zA;
        const float zg = lo ? zB : sB;
        const float zo = lo ? sB : zB;

        const float ig = sigm(zi);
        const float fg = sigm(zf);
        const float gg = tanh_fast(zg);
        const float og = sigm(zo);
        const float cn = __builtin_fmaf(fg, c, ig * gg);
        const float hn = og * tanh_fast(cn);

        const bool m = (tok0 != 0);
        c    = m ? cn : c;
        hval = m ? hn : hval;

        tok0 = tok1; tok1 = tok2; tok2 = tok3;
        xz0 = xz1; xz1 = xz2;
    }

    if (lo) out[(size_t)b * HIDN + l] = hval;
}

extern "C" void kernel_launch(void* const* d_in, const int* in_sizes, int n_in,
                              void* d_out, int out_size, void* d_ws, size_t ws_size,
                              hipStream_t stream)
{
    const int*   tokens = (const int*)d_in[0];
    const float* emb    = (const float*)d_in[1];
    const float* W      = (const float*)d_in[2];
    const float* rec    = (const float*)d_in[3];
    const float* bias   = (const float*)d_in[4];
    float* out = (float*)d_out;
    v2f* proj = (v2f*)d_ws;   // VOCABN*64 v2f = 2.56 MB

    hipLaunchKernelGGL(build_proj_kernel, dim3(VOCABN), dim3(64), 0, stream,
                       emb, W, bias, proj);
    hipLaunchKernelGGL(lstm_scan_kernel, dim3(BATCH), dim3(64), 0, stream,
                       tokens, rec, proj, out);
}

// Round 6
// 777.579 us; speedup vs baseline: 2.7101x; 2.7101x over previous
//
#include <hip/hip_runtime.h>

#define VOCABN 5000
#define EMBD   16
#define HIDN   32
#define GATES  128   // 4*HID
#define BATCH  512
#define SEQT   2048

__device__ __forceinline__ float sigm(float x) {
    return __builtin_amdgcn_rcpf(1.0f + __expf(-x));
}
__device__ __forceinline__ float tanh_fast(float x) {
    float s = __builtin_amdgcn_rcpf(1.0f + __expf(-2.0f * x));
    return __builtin_fmaf(2.0f, s, -1.0f);
}

// proj4[v*32 + j] = { xz_i, xz_f, xz_g, xz_o } for hidden unit j:
//   gate columns j, j+32, j+64, j+96 of (emb[v] @ W + bias)
__global__ __launch_bounds__(64) void build_proj_kernel(
    const float* __restrict__ emb, const float* __restrict__ W,
    const float* __restrict__ bias, float4* __restrict__ proj4)
{
    const int v = blockIdx.x;
    const int l = threadIdx.x;
    if (l >= HIDN) return;
    float e[EMBD];
#pragma unroll
    for (int k = 0; k < EMBD; ++k) e[k] = emb[v * EMBD + k];
    float zi = bias[l];
    float zf = bias[l + 32];
    float zg = bias[l + 64];
    float zo = bias[l + 96];
#pragma unroll
    for (int k = 0; k < EMBD; ++k) {
        zi = __builtin_fmaf(e[k], W[k * GATES + l],      zi);
        zf = __builtin_fmaf(e[k], W[k * GATES + l + 32], zf);
        zg = __builtin_fmaf(e[k], W[k * GATES + l + 64], zg);
        zo = __builtin_fmaf(e[k], W[k * GATES + l + 96], zo);
    }
    proj4[v * HIDN + l] = make_float4(zi, zf, zg, zo);
}

// One 64-lane wave per batch row. Lane l owns ALL FOUR gates of hidden unit
// j = l&31 (upper half redundant). h-broadcast via v_readlane -> SGPR, used
// directly as the scalar operand of v_fma_f32: ZERO DS ops in the step loop,
// so no lgkmcnt stalls (the R1 ds_swizzle version paid ~120cy x32 per step).
__global__ __launch_bounds__(64) void lstm_scan_kernel(
    const int* __restrict__ tokens, const float* __restrict__ rec,
    const float4* __restrict__ proj4, float* __restrict__ out)
{
    const int b = blockIdx.x;
    const int l = threadIdx.x;
    const int j = l & 31;

    // rec columns for unit j's four gates: 128 VGPRs, resident all scan
    float ri[HIDN], rf[HIDN], rg[HIDN], ro[HIDN];
#pragma unroll
    for (int k = 0; k < HIDN; ++k) {
        ri[k] = rec[k * GATES + j];
        rf[k] = rec[k * GATES + j + 32];
        rg[k] = rec[k * GATES + j + 64];
        ro[k] = rec[k * GATES + j + 96];
    }

    const int* __restrict__ trow = tokens + (size_t)b * SEQT;

    float c = 0.0f, hval = 0.0f;

    // depth-2 prefetch for the proj4 gather (L2-resident, ~200-300 cy)
    int tok0 = trow[0];
    int tok1 = trow[1];
    int tok2 = trow[2];
    float4 xz0 = proj4[(size_t)tok0 * HIDN + j];
    float4 xz1 = proj4[(size_t)tok1 * HIDN + j];

    for (int t = 0; t < SEQT; ++t) {
        float4 xz2 = proj4[(size_t)tok2 * HIDN + j];
        const int t3 = t + 3;
        const int tok3 = trow[t3 < SEQT ? t3 : SEQT - 1];

        // z[gate] = xz[gate] + sum_k h[k] * rec[k][gate-col], 2-way split accs
        float zi0 = xz0.x, zf0 = xz0.y, zg0 = xz0.z, zo0 = xz0.w;
        float zi1 = 0.f, zf1 = 0.f, zg1 = 0.f, zo1 = 0.f;
#pragma unroll
        for (int k = 0; k < HIDN; k += 2) {
            const float hk0 = __int_as_float(
                __builtin_amdgcn_readlane(__float_as_int(hval), k));
            const float hk1 = __int_as_float(
                __builtin_amdgcn_readlane(__float_as_int(hval), k + 1));
            zi0 = __builtin_fmaf(hk0, ri[k], zi0);
            zf0 = __builtin_fmaf(hk0, rf[k], zf0);
            zg0 = __builtin_fmaf(hk0, rg[k], zg0);
            zo0 = __builtin_fmaf(hk0, ro[k], zo0);
            zi1 = __builtin_fmaf(hk1, ri[k + 1], zi1);
            zf1 = __builtin_fmaf(hk1, rf[k + 1], zf1);
            zg1 = __builtin_fmaf(hk1, rg[k + 1], zg1);
            zo1 = __builtin_fmaf(hk1, ro[k + 1], zo1);
        }
        const float zi = zi0 + zi1;
        const float zf = zf0 + zf1;
        const float zg = zg0 + zg1;
        const float zo = zo0 + zo1;

        const float ig = sigm(zi);
        const float fg = sigm(zf);
        const float gg = tanh_fast(zg);
        const float og = sigm(zo);
        const float cn = __builtin_fmaf(fg, c, ig * gg);
        const float hn = og * tanh_fast(cn);

        const bool m = (tok0 != 0);   // wave-uniform
        c    = m ? cn : c;
        hval = m ? hn : hval;

        tok0 = tok1; tok1 = tok2; tok2 = tok3;
        xz0 = xz1; xz1 = xz2;
    }

    if (l < HIDN) out[(size_t)b * HIDN + j] = hval;
}

extern "C" void kernel_launch(void* const* d_in, const int* in_sizes, int n_in,
                              void* d_out, int out_size, void* d_ws, size_t ws_size,
                              hipStream_t stream)
{
    const int*   tokens = (const int*)d_in[0];
    const float* emb    = (const float*)d_in[1];
    const float* W      = (const float*)d_in[2];
    const float* rec    = (const float*)d_in[3];
    const float* bias   = (const float*)d_in[4];
    float* out = (float*)d_out;
    float4* proj4 = (float4*)d_ws;   // VOCABN*32 float4 = 2.56 MB

    hipLaunchKernelGGL(build_proj_kernel, dim3(VOCABN), dim3(64), 0, stream,
                       emb, W, bias, proj4);
    hipLaunchKernelGGL(lstm_scan_kernel, dim3(BATCH), dim3(64), 0, stream,
                       tokens, rec, proj4, out);
}

// Round 7
// 639.355 us; speedup vs baseline: 3.2960x; 1.2162x over previous
//
#include <hip/hip_runtime.h>

typedef float v2f __attribute__((ext_vector_type(2)));

#define VOCABN 5000
#define EMBD   16
#define HIDN   32
#define GATES  128   // 4*HID
#define BATCH  512
#define SEQT   2048

// Gate pre-scales folded into proj table and rec columns:
//   sigmoid(z) = 1/(1+exp2(S1*z)),  S1 = -log2(e)
//   tanh(z)    = 2/(1+exp2(S2*z))-1, S2 = -2*log2(e)
#define S1f (-1.4426950408889634f)
#define S2f (-2.8853900817779268f)

__device__ __forceinline__ float rcp1p2(float x) {   // 1/(1+2^x)
    return __builtin_amdgcn_rcpf(1.0f + __builtin_amdgcn_exp2f(x));
}

// proj4[v*32 + j] = pre-scaled { S1*zi, S1*zf, S2*zg, S1*zo } for hidden unit j
__global__ __launch_bounds__(64) void build_proj_kernel(
    const float* __restrict__ emb, const float* __restrict__ W,
    const float* __restrict__ bias, float4* __restrict__ proj4)
{
    const int v = blockIdx.x;
    const int l = threadIdx.x;
    if (l >= HIDN) return;
    float e[EMBD];
#pragma unroll
    for (int k = 0; k < EMBD; ++k) e[k] = emb[v * EMBD + k];
    float zi = bias[l];
    float zf = bias[l + 32];
    float zg = bias[l + 64];
    float zo = bias[l + 96];
#pragma unroll
    for (int k = 0; k < EMBD; ++k) {
        zi = __builtin_fmaf(e[k], W[k * GATES + l],      zi);
        zf = __builtin_fmaf(e[k], W[k * GATES + l + 32], zf);
        zg = __builtin_fmaf(e[k], W[k * GATES + l + 64], zg);
        zo = __builtin_fmaf(e[k], W[k * GATES + l + 96], zo);
    }
    proj4[v * HIDN + l] = make_float4(S1f * zi, S1f * zf, S2f * zg, S1f * zo);
}

// One 64-lane wave per batch row; lane l owns all 4 gates of unit j=l&31
// (upper half redundant). h-broadcast via v_readlane (zero DS ops). Gate
// pairs (i,f) and (g,o) accumulate as v2f -> v_pk_fma_f32, 4-way split
// accumulators (8-deep chains). All gate z's pre-scaled so activations are
// rcp(1+exp2(z)) with no leading multiply on the critical path.
__global__ __launch_bounds__(64) void lstm_scan_kernel(
    const int* __restrict__ tokens, const float* __restrict__ rec,
    const float4* __restrict__ proj4, float* __restrict__ out)
{
    const int b = blockIdx.x;
    const int l = threadIdx.x;
    const int j = l & 31;

    // Pre-scaled rec columns for unit j, packed per gate pair (128 VGPRs)
    v2f Rif[HIDN], Rgo[HIDN];
#pragma unroll
    for (int k = 0; k < HIDN; ++k) {
        Rif[k] = (v2f){ S1f * rec[k * GATES + j],      S1f * rec[k * GATES + j + 32] };
        Rgo[k] = (v2f){ S2f * rec[k * GATES + j + 64], S1f * rec[k * GATES + j + 96] };
    }

    const int* __restrict__ trow = tokens + (size_t)b * SEQT;

    float c = 0.0f, hval = 0.0f;

    int tok0 = trow[0];
    int tok1 = trow[1];
    int tok2 = trow[2];
    float4 xz0 = proj4[(size_t)tok0 * HIDN + j];
    float4 xz1 = proj4[(size_t)tok1 * HIDN + j];

#pragma unroll 2
    for (int t = 0; t < SEQT; ++t) {
        float4 xz2 = proj4[(size_t)tok2 * HIDN + j];
        const int t3 = t + 3;
        const int tok3 = trow[t3 < SEQT ? t3 : SEQT - 1];

        // z = xz + h @ rec ; packed gate pairs, 4-way split accumulators
        v2f aif[4], ago[4];
        aif[0] = (v2f){ xz0.x, xz0.y };
        ago[0] = (v2f){ xz0.z, xz0.w };
#pragma unroll
        for (int q = 1; q < 4; ++q) {
            aif[q] = (v2f){ 0.f, 0.f };
            ago[q] = (v2f){ 0.f, 0.f };
        }
#pragma unroll
        for (int k = 0; k < HIDN; ++k) {
            const float hk = __int_as_float(
                __builtin_amdgcn_readlane(__float_as_int(hval), k));
            const v2f hh = (v2f){ hk, hk };
            aif[k & 3] = __builtin_elementwise_fma(hh, Rif[k], aif[k & 3]);
            ago[k & 3] = __builtin_elementwise_fma(hh, Rgo[k], ago[k & 3]);
        }
        const v2f zif = (aif[0] + aif[1]) + (aif[2] + aif[3]);
        const v2f zgo = (ago[0] + ago[1]) + (ago[2] + ago[3]);

        const float ig = rcp1p2(zif.x);
        const float fg = rcp1p2(zif.y);
        const float gg = __builtin_fmaf(2.0f, rcp1p2(zgo.x), -1.0f);
        const float og = rcp1p2(zgo.y);
        const float cn = __builtin_fmaf(fg, c, ig * gg);
        const float tc = __builtin_fmaf(2.0f, rcp1p2(S2f * cn), -1.0f);
        const float hn = og * tc;

        const bool m = (tok0 != 0);   // wave-uniform
        c    = m ? cn : c;
        hval = m ? hn : hval;

        tok0 = tok1; tok1 = tok2; tok2 = tok3;
        xz0 = xz1; xz1 = xz2;
    }

    if (l < HIDN) out[(size_t)b * HIDN + j] = hval;
}

extern "C" void kernel_launch(void* const* d_in, const int* in_sizes, int n_in,
                              void* d_out, int out_size, void* d_ws, size_t ws_size,
                              hipStream_t stream)
{
    const int*   tokens = (const int*)d_in[0];
    const float* emb    = (const float*)d_in[1];
    const float* W      = (const float*)d_in[2];
    const float* rec    = (const float*)d_in[3];
    const float* bias   = (const float*)d_in[4];
    float* out = (float*)d_out;
    float4* proj4 = (float4*)d_ws;   // VOCABN*32 float4 = 2.56 MB

    hipLaunchKernelGGL(build_proj_kernel, dim3(VOCABN), dim3(64), 0, stream,
                       emb, W, bias, proj4);
    hipLaunchKernelGGL(lstm_scan_kernel, dim3(BATCH), dim3(64), 0, stream,
                       tokens, rec, proj4, out);
}

// Round 9
// 506.184 us; speedup vs baseline: 4.1632x; 1.2631x over previous
//
#include <hip/hip_runtime.h>

typedef float v2f __attribute__((ext_vector_type(2)));

#define VOCABN 5000
#define EMBD   16
#define HIDN   32
#define GATES  128   // 4*HID
#define BATCH  512
#define SEQT   2048

// Gate pre-scales folded into proj table and rec columns:
//   sigmoid(z) = 1/(1+exp2(S1*z)),  S1 = -log2(e)
//   tanh(z)    = 2/(1+exp2(S2*z))-1, S2 = -2*log2(e)
#define S1f (-1.4426950408889634f)
#define S2f (-2.8853900817779268f)

__device__ __forceinline__ float rcp1p2(float x) {   // 1/(1+2^x)
    return __builtin_amdgcn_rcpf(1.0f + __builtin_amdgcn_exp2f(x));
}

// Gate-split proj table, one v2f per (token, lane):
//   lane l<32  (j=l):    { S1*z_i[j], S2*z_g[j] }
//   lane l>=32 (j=l-32): { S1*z_f[j], S1*z_o[j] }
__global__ __launch_bounds__(64, 1) void build_proj_kernel(
    const float* __restrict__ emb, const float* __restrict__ W,
    const float* __restrict__ bias, v2f* __restrict__ proj2)
{
    const int v = blockIdx.x;
    const int l = threadIdx.x;
    const int j = l & 31;
    const int half = l >> 5;
    const int c0 = j + half * 32;        // i (lower) / f (upper)
    const int c1 = j + 64 + half * 32;   // g (lower) / o (upper)
    const float sc1 = half ? S1f : S2f;

    float e[EMBD];
#pragma unroll
    for (int k = 0; k < EMBD; ++k) e[k] = emb[v * EMBD + k];
    float z0 = bias[c0];
    float z1 = bias[c1];
#pragma unroll
    for (int k = 0; k < EMBD; ++k) {
        z0 = __builtin_fmaf(e[k], W[k * GATES + c0], z0);
        z1 = __builtin_fmaf(e[k], W[k * GATES + c1], z1);
    }
    proj2[(size_t)v * 64 + l] = (v2f){ S1f * z0, sc1 * z1 };
}

// One 64-lane wave per batch row, gates split across halves:
//   lower lane j:  accumulates (i,g) of unit j -> ig, gg; p = ig*gg
//   upper lane j+32: accumulates (f,o); receives p via shfl_xor(32);
//                    computes cn = fg*c + p, hn = og*tanh(cn).
// h and c live in the UPPER half; h-broadcast via v_readlane(hval, 32+k).
// launch_bounds(64,1): allow full VGPR budget so the 32 v2f rec columns stay
// register-resident (previous rounds silently spilled them to scratch:
// VGPR_Count=80 < the 128 required).
__global__ __launch_bounds__(64, 1) void lstm_scan_kernel(
    const int* __restrict__ tokens, const float* __restrict__ rec,
    const v2f* __restrict__ proj2, float* __restrict__ out)
{
    const int b = blockIdx.x;
    const int l = threadIdx.x;
    const int j = l & 31;
    const int half = l >> 5;
    const int c0 = j + half * 32;
    const int c1 = j + 64 + half * 32;
    const float sc1 = half ? S1f : S2f;

    // Pre-scaled rec columns for this lane's gate pair (64 VGPRs)
    v2f R2[HIDN];
#pragma unroll
    for (int k = 0; k < HIDN; ++k) {
        R2[k] = (v2f){ S1f * rec[k * GATES + c0], sc1 * rec[k * GATES + c1] };
    }

    const int* __restrict__ trow = tokens + (size_t)b * SEQT;

    float c = 0.0f, hval = 0.0f;

    int tok0 = trow[0];
    int tok1 = trow[1];
    int tok2 = trow[2];
    v2f xz0 = proj2[(size_t)tok0 * 64 + l];
    v2f xz1 = proj2[(size_t)tok1 * 64 + l];

#pragma unroll 2
    for (int t = 0; t < SEQT; ++t) {
        v2f xz2 = proj2[(size_t)tok2 * 64 + l];
        const int t3 = t + 3;
        const int tok3 = trow[t3 < SEQT ? t3 : SEQT - 1];

        // z = xz + h @ rec (this lane's gate pair); 4-way split accumulators
        v2f a0 = xz0;
        v2f a1 = (v2f){0.f, 0.f};
        v2f a2 = (v2f){0.f, 0.f};
        v2f a3 = (v2f){0.f, 0.f};
#pragma unroll
        for (int k = 0; k < HIDN; k += 4) {
            const float h0 = __int_as_float(
                __builtin_amdgcn_readlane(__float_as_int(hval), 32 + k));
            const float h1 = __int_as_float(
                __builtin_amdgcn_readlane(__float_as_int(hval), 32 + k + 1));
            const float h2 = __int_as_float(
                __builtin_amdgcn_readlane(__float_as_int(hval), 32 + k + 2));
            const float h3 = __int_as_float(
                __builtin_amdgcn_readlane(__float_as_int(hval), 32 + k + 3));
            a0 = __builtin_elementwise_fma((v2f){h0, h0}, R2[k],     a0);
            a1 = __builtin_elementwise_fma((v2f){h1, h1}, R2[k + 1], a1);
            a2 = __builtin_elementwise_fma((v2f){h2, h2}, R2[k + 2], a2);
            a3 = __builtin_elementwise_fma((v2f){h3, h3}, R2[k + 3], a3);
        }
        const v2f z = (a0 + a1) + (a2 + a3);

        // activations (shared instruction stream, per-half meaning):
        const float u = rcp1p2(z.x);                    // lower: ig ; upper: fg
        const float w = rcp1p2(z.y);                    // lower: gg'; upper: og
        const float gg = __builtin_fmaf(2.0f, w, -1.0f);// lower: tanh(zg)
        const float p = u * gg;                         // lower: ig*gg
        const float ps = __shfl_xor(p, 32, 64);         // upper <- lower's p

        const float cn = __builtin_fmaf(u, c, ps);      // upper: fg*c + ig*gg
        const float tc = __builtin_fmaf(2.0f, rcp1p2(S2f * cn), -1.0f);
        const float hn = w * tc;                        // upper: og*tanh(cn)

        const bool m = (tok0 != 0);   // wave-uniform
        c    = m ? cn : c;
        hval = m ? hn : hval;

        tok0 = tok1; tok1 = tok2; tok2 = tok3;
        xz0 = xz1; xz1 = xz2;
    }

    if (half) out[(size_t)b * HIDN + j] = hval;
}

extern "C" void kernel_launch(void* const* d_in, const int* in_sizes, int n_in,
                              void* d_out, int out_size, void* d_ws, size_t ws_size,
                              hipStream_t stream)
{
    const int*   tokens = (const int*)d_in[0];
    const float* emb    = (const float*)d_in[1];
    const float* W      = (const float*)d_in[2];
    const float* rec    = (const float*)d_in[3];
    const float* bias   = (const float*)d_in[4];
    float* out = (float*)d_out;
    v2f* proj2 = (v2f*)d_ws;   // VOCABN*64 v2f = 2.56 MB

    hipLaunchKernelGGL(build_proj_kernel, dim3(VOCABN), dim3(64), 0, stream,
                       emb, W, bias, proj2);
    hipLaunchKernelGGL(lstm_scan_kernel, dim3(BATCH), dim3(64), 0, stream,
                       tokens, rec, proj2, out);
}